// Round 4
// baseline (106.519 us; speedup 1.0000x reference)
//
#include <hip/hip_runtime.h>

#define THREADS 256
#define BLOCKS 2048   // 256 CUs * 8 blocks/CU

typedef float nfloat4 __attribute__((ext_vector_type(4)));

// d_ws layout: [0..BLOCKS) partial floats | counter (1 uint) at offset BLOCKS

__global__ __launch_bounds__(THREADS) void sum_fused(
    const nfloat4* __restrict__ x, float* __restrict__ partials,
    unsigned int* __restrict__ counter, float* __restrict__ out, int n4) {
    float s = 0.0f;
    for (int i = blockIdx.x * blockDim.x + threadIdx.x; i < n4;
         i += gridDim.x * blockDim.x) {
        nfloat4 v = __builtin_nontemporal_load(&x[i]);
        s += (v.x + v.y) + (v.z + v.w);
    }
    // wave-64 butterfly reduce
    #pragma unroll
    for (int off = 32; off > 0; off >>= 1)
        s += __shfl_down(s, off, 64);
    __shared__ float lds[THREADS / 64];
    const int lane = threadIdx.x & 63;
    const int wave = threadIdx.x >> 6;
    if (lane == 0) lds[wave] = s;
    __syncthreads();

    __shared__ bool is_last;
    if (threadIdx.x == 0) {
        float t = 0.0f;
        #pragma unroll
        for (int w = 0; w < THREADS / 64; ++w) t += lds[w];
        partials[blockIdx.x] = t;
        __threadfence();                       // release partial (device scope)
        unsigned int prev = atomicAdd(counter, 1u);
        is_last = (prev == gridDim.x - 1);
    }
    __syncthreads();
    if (!is_last) return;

    // last block: fold all partials, deterministic fixed-order tree
    __threadfence();                           // acquire
    const volatile float* vp = (const volatile float*)partials;
    float t = 0.0f;
    for (int i = threadIdx.x; i < BLOCKS; i += THREADS) t += vp[i];
    #pragma unroll
    for (int off = 32; off > 0; off >>= 1)
        t += __shfl_down(t, off, 64);
    if (lane == 0) lds[wave] = t;
    __syncthreads();
    if (threadIdx.x == 0) {
        float r = 0.0f;
        #pragma unroll
        for (int w = 0; w < THREADS / 64; ++w) r += lds[w];
        out[0] = r;
    }
}

extern "C" void kernel_launch(void* const* d_in, const int* in_sizes, int n_in,
                              void* d_out, int out_size, void* d_ws, size_t ws_size,
                              hipStream_t stream) {
    const float* x = (const float*)d_in[0];
    float* out = (float*)d_out;
    float* partials = (float*)d_ws;                        // BLOCKS floats
    unsigned int* counter = (unsigned int*)(partials + BLOCKS);

    const int n = in_sizes[0];        // 64*1024*1024, divisible by 4
    const int n4 = n / 4;

    (void)hipMemsetAsync(counter, 0, sizeof(unsigned int), stream);
    sum_fused<<<BLOCKS, THREADS, 0, stream>>>((const nfloat4*)x, partials,
                                              counter, out, n4);
}

// Round 5
// 98.650 us; speedup vs baseline: 1.0798x; 1.0798x over previous
//
#include <hip/hip_runtime.h>

#define THREADS 256
#define BLOCKS 2048   // 256 CUs * 8 blocks/CU

// d_ws layout: [0..BLOCKS) partial floats | counter (1 uint) at offset BLOCKS

__global__ __launch_bounds__(THREADS) void sum_fused(
    const float4* __restrict__ x, float* __restrict__ partials,
    unsigned int* __restrict__ counter, float* __restrict__ out, int n4) {
    float s = 0.0f;
    for (int i = blockIdx.x * blockDim.x + threadIdx.x; i < n4;
         i += gridDim.x * blockDim.x) {
        float4 v = x[i];
        s += (v.x + v.y) + (v.z + v.w);
    }
    // wave-64 butterfly reduce
    #pragma unroll
    for (int off = 32; off > 0; off >>= 1)
        s += __shfl_down(s, off, 64);
    __shared__ float lds[THREADS / 64];
    const int lane = threadIdx.x & 63;
    const int wave = threadIdx.x >> 6;
    if (lane == 0) lds[wave] = s;
    __syncthreads();

    __shared__ bool is_last;
    if (threadIdx.x == 0) {
        float t = 0.0f;
        #pragma unroll
        for (int w = 0; w < THREADS / 64; ++w) t += lds[w];
        partials[blockIdx.x] = t;
        __threadfence();                       // release partial (device scope)
        unsigned int prev = atomicAdd(counter, 1u);
        is_last = (prev == gridDim.x - 1);
    }
    __syncthreads();
    if (!is_last) return;

    // last block: fold all partials, deterministic fixed-order tree
    __threadfence();                           // acquire
    const volatile float* vp = (const volatile float*)partials;
    float t = 0.0f;
    for (int i = threadIdx.x; i < BLOCKS; i += THREADS) t += vp[i];
    #pragma unroll
    for (int off = 32; off > 0; off >>= 1)
        t += __shfl_down(t, off, 64);
    if (lane == 0) lds[wave] = t;
    __syncthreads();
    if (threadIdx.x == 0) {
        float r = 0.0f;
        #pragma unroll
        for (int w = 0; w < THREADS / 64; ++w) r += lds[w];
        out[0] = r;
    }
}

extern "C" void kernel_launch(void* const* d_in, const int* in_sizes, int n_in,
                              void* d_out, int out_size, void* d_ws, size_t ws_size,
                              hipStream_t stream) {
    const float* x = (const float*)d_in[0];
    float* out = (float*)d_out;
    float* partials = (float*)d_ws;                        // BLOCKS floats
    unsigned int* counter = (unsigned int*)(partials + BLOCKS);

    const int n = in_sizes[0];        // 64*1024*1024, divisible by 4
    const int n4 = n / 4;

    (void)hipMemsetAsync(counter, 0, sizeof(unsigned int), stream);
    sum_fused<<<BLOCKS, THREADS, 0, stream>>>((const float4*)x, partials,
                                              counter, out, n4);
}

// Round 6
// 51.122 us; speedup vs baseline: 2.0836x; 1.9297x over previous
//
#include <hip/hip_runtime.h>

#define THREADS 256
#define BLOCKS 2048
#define STRIDE (BLOCKS * THREADS)   // 524288 threads

// 4-way unrolled strided read: 4 independent dwordx4 loads in flight per lane,
// 4 independent accumulators (breaks the add dependence chain).
__global__ __launch_bounds__(THREADS) void sum_stage1(
    const float4* __restrict__ x, float* __restrict__ partials, int n4) {
    const int tid = blockIdx.x * THREADS + threadIdx.x;
    float s0 = 0.f, s1 = 0.f, s2 = 0.f, s3 = 0.f;

    const int n_groups = n4 / (4 * STRIDE);   // 8 for 64Mi elements
    int i = tid;
    for (int g = 0; g < n_groups; ++g) {
        float4 a = x[i];
        float4 b = x[i + STRIDE];
        float4 c = x[i + 2 * STRIDE];
        float4 d = x[i + 3 * STRIDE];
        i += 4 * STRIDE;
        s0 += (a.x + a.y) + (a.z + a.w);
        s1 += (b.x + b.y) + (b.z + b.w);
        s2 += (c.x + c.y) + (c.z + c.w);
        s3 += (d.x + d.y) + (d.z + d.w);
    }
    for (; i < n4; i += STRIDE) {             // tail (empty for 64Mi)
        float4 a = x[i];
        s0 += (a.x + a.y) + (a.z + a.w);
    }
    float s = (s0 + s1) + (s2 + s3);

    #pragma unroll
    for (int off = 32; off > 0; off >>= 1)
        s += __shfl_down(s, off, 64);
    __shared__ float lds[THREADS / 64];
    const int lane = threadIdx.x & 63;
    const int wave = threadIdx.x >> 6;
    if (lane == 0) lds[wave] = s;
    __syncthreads();
    if (threadIdx.x == 0) {
        float t = 0.f;
        #pragma unroll
        for (int w = 0; w < THREADS / 64; ++w) t += lds[w];
        partials[blockIdx.x] = t;
    }
}

__global__ __launch_bounds__(THREADS) void sum_stage2(
    const float* __restrict__ partials, float* __restrict__ out, int n) {
    float s = 0.f;
    for (int i = threadIdx.x; i < n; i += blockDim.x) s += partials[i];
    #pragma unroll
    for (int off = 32; off > 0; off >>= 1)
        s += __shfl_down(s, off, 64);
    __shared__ float lds[THREADS / 64];
    const int lane = threadIdx.x & 63;
    const int wave = threadIdx.x >> 6;
    if (lane == 0) lds[wave] = s;
    __syncthreads();
    if (threadIdx.x == 0) {
        float t = 0.f;
        #pragma unroll
        for (int w = 0; w < THREADS / 64; ++w) t += lds[w];
        out[0] = t;
    }
}

extern "C" void kernel_launch(void* const* d_in, const int* in_sizes, int n_in,
                              void* d_out, int out_size, void* d_ws, size_t ws_size,
                              hipStream_t stream) {
    const float* x = (const float*)d_in[0];
    float* out = (float*)d_out;
    float* partials = (float*)d_ws;   // BLOCKS floats = 8 KiB scratch

    const int n = in_sizes[0];        // 64*1024*1024, divisible by 4
    const int n4 = n / 4;

    sum_stage1<<<BLOCKS, THREADS, 0, stream>>>((const float4*)x, partials, n4);
    sum_stage2<<<1, THREADS, 0, stream>>>(partials, out, BLOCKS);
}

// Round 7
// 44.532 us; speedup vs baseline: 2.3920x; 1.1480x over previous
//
#include <hip/hip_runtime.h>

#define THREADS 256
#define BLOCKS 2048
#define UNROLL 8

// Each block owns a contiguous chunk; 8 independent dwordx4 loads in flight
// per lane, spaced THREADS*16B = 4 KiB apart (locally contiguous — no
// power-of-2 channel aliasing), 8 independent accumulators.
__global__ __launch_bounds__(THREADS) void sum_stage1(
    const float4* __restrict__ x, float* __restrict__ partials, int n4) {
    const int per_block = n4 / BLOCKS;            // 8192 float4 = 512 KiB
    const int base = blockIdx.x * per_block;
    const int iters = per_block / (UNROLL * THREADS);  // 4

    float s[UNROLL];
    #pragma unroll
    for (int k = 0; k < UNROLL; ++k) s[k] = 0.f;

    int i = base + threadIdx.x;
    for (int g = 0; g < iters; ++g) {
        float4 v[UNROLL];
        #pragma unroll
        for (int k = 0; k < UNROLL; ++k) v[k] = x[i + k * THREADS];
        i += UNROLL * THREADS;
        #pragma unroll
        for (int k = 0; k < UNROLL; ++k)
            s[k] += (v[k].x + v[k].y) + (v[k].z + v[k].w);
    }
    // tail (empty for 64Mi elements; kept for generality)
    for (int j = base + iters * UNROLL * THREADS + threadIdx.x;
         j < base + per_block; j += THREADS) {
        float4 a = x[j];
        s[0] += (a.x + a.y) + (a.z + a.w);
    }

    float s01 = s[0] + s[1], s23 = s[2] + s[3];
    float s45 = s[4] + s[5], s67 = s[6] + s[7];
    float sum = (s01 + s23) + (s45 + s67);

    #pragma unroll
    for (int off = 32; off > 0; off >>= 1)
        sum += __shfl_down(sum, off, 64);
    __shared__ float lds[THREADS / 64];
    const int lane = threadIdx.x & 63;
    const int wave = threadIdx.x >> 6;
    if (lane == 0) lds[wave] = sum;
    __syncthreads();
    if (threadIdx.x == 0) {
        float t = 0.f;
        #pragma unroll
        for (int w = 0; w < THREADS / 64; ++w) t += lds[w];
        partials[blockIdx.x] = t;
    }
}

#define S2_THREADS 1024

__global__ __launch_bounds__(S2_THREADS) void sum_stage2(
    const float* __restrict__ partials, float* __restrict__ out, int n) {
    float s = 0.f;
    for (int i = threadIdx.x; i < n; i += S2_THREADS) s += partials[i];
    #pragma unroll
    for (int off = 32; off > 0; off >>= 1)
        s += __shfl_down(s, off, 64);
    __shared__ float lds[S2_THREADS / 64];
    const int lane = threadIdx.x & 63;
    const int wave = threadIdx.x >> 6;
    if (lane == 0) lds[wave] = s;
    __syncthreads();
    if (threadIdx.x == 0) {
        float t = 0.f;
        #pragma unroll
        for (int w = 0; w < S2_THREADS / 64; ++w) t += lds[w];
        out[0] = t;
    }
}

extern "C" void kernel_launch(void* const* d_in, const int* in_sizes, int n_in,
                              void* d_out, int out_size, void* d_ws, size_t ws_size,
                              hipStream_t stream) {
    const float* x = (const float*)d_in[0];
    float* out = (float*)d_out;
    float* partials = (float*)d_ws;   // BLOCKS floats = 8 KiB scratch

    const int n = in_sizes[0];        // 64*1024*1024
    const int n4 = n / 4;

    sum_stage1<<<BLOCKS, THREADS, 0, stream>>>((const float4*)x, partials, n4);
    sum_stage2<<<1, S2_THREADS, 0, stream>>>(partials, out, BLOCKS);
}